// Round 1
// baseline (151.390 us; speedup 1.0000x reference)
//
#include <hip/hip_runtime.h>

#define NBATCH 64
#define NV 50000
#define NT 100000
#define FPB (NV * 3)      /* floats per batch = 150000 */
#define CHUNKS 128        /* blocks per batch in volume pass */

__global__ __launch_bounds__(256) void vol_partial_kernel(
    const float* __restrict__ x, const int* __restrict__ M,
    double* __restrict__ partials) {
  const int b = blockIdx.y;
  const float* __restrict__ xv = x + (size_t)b * FPB;
  double acc = 0.0;
  const int stride = blockDim.x * gridDim.x;
  for (int t = blockIdx.x * blockDim.x + threadIdx.x; t < NT; t += stride) {
    const int i0 = M[3 * t + 0];
    const int i1 = M[3 * t + 1];
    const int i2 = M[3 * t + 2];
    const float a0 = xv[3 * i0 + 0], a1 = xv[3 * i0 + 1], a2 = xv[3 * i0 + 2];
    const float b0 = xv[3 * i1 + 0], b1 = xv[3 * i1 + 1], b2 = xv[3 * i1 + 2];
    const float c0 = xv[3 * i2 + 0], c1 = xv[3 * i2 + 1], c2 = xv[3 * i2 + 2];
    const float cx = b1 * c2 - b2 * c1;
    const float cy = b2 * c0 - b0 * c2;
    const float cz = b0 * c1 - b1 * c0;
    const float det = a0 * cx + a1 * cy + a2 * cz;
    acc += (double)fabsf(det);
  }
  // wave (64-lane) reduce
  #pragma unroll
  for (int off = 32; off > 0; off >>= 1) acc += __shfl_down(acc, off, 64);
  __shared__ double lds[4];
  const int lane = threadIdx.x & 63;
  const int wave = threadIdx.x >> 6;
  if (lane == 0) lds[wave] = acc;
  __syncthreads();
  if (threadIdx.x == 0) {
    const double s = (lds[0] + lds[1]) + (lds[2] + lds[3]);
    partials[(size_t)b * gridDim.x + blockIdx.x] = s;
  }
}

__global__ __launch_bounds__(CHUNKS) void finalize_kernel(
    const double* __restrict__ partials, float* __restrict__ inv_scale) {
  const int b = blockIdx.x;
  double v = partials[(size_t)b * CHUNKS + threadIdx.x];
  #pragma unroll
  for (int off = 32; off > 0; off >>= 1) v += __shfl_down(v, off, 64);
  __shared__ double lds[2];
  const int lane = threadIdx.x & 63;
  const int wave = threadIdx.x >> 6;
  if (lane == 0) lds[wave] = v;
  __syncthreads();
  if (threadIdx.x == 0) {
    const double vol = (lds[0] + lds[1]) / 6.0;
    const double scale = cbrt(vol);
    inv_scale[b] = (float)(1.0 / scale);
  }
}

__global__ __launch_bounds__(256) void normalize_kernel(
    const float* __restrict__ x, const float* __restrict__ inv_scale,
    float* __restrict__ out) {
  const int b = blockIdx.y;
  const float s = inv_scale[b];
  const float4* __restrict__ xin =
      reinterpret_cast<const float4*>(x + (size_t)b * FPB);
  float4* __restrict__ o = reinterpret_cast<float4*>(out + (size_t)b * FPB);
  const int n4 = FPB / 4;  // 37500, FPB divisible by 4
  const int stride = blockDim.x * gridDim.x;
  for (int i = blockIdx.x * blockDim.x + threadIdx.x; i < n4; i += stride) {
    float4 v = xin[i];
    v.x *= s; v.y *= s; v.z *= s; v.w *= s;
    o[i] = v;
  }
}

extern "C" void kernel_launch(void* const* d_in, const int* in_sizes, int n_in,
                              void* d_out, int out_size, void* d_ws, size_t ws_size,
                              hipStream_t stream) {
  const float* x = (const float*)d_in[0];
  const int* M = (const int*)d_in[1];
  float* out = (float*)d_out;

  double* partials = (double*)d_ws;                       // NBATCH*CHUNKS doubles = 64 KiB
  float* inv_scale = (float*)(partials + NBATCH * CHUNKS);  // NBATCH floats

  dim3 gridA(CHUNKS, NBATCH);
  vol_partial_kernel<<<gridA, 256, 0, stream>>>(x, M, partials);

  finalize_kernel<<<NBATCH, CHUNKS, 0, stream>>>(partials, inv_scale);

  dim3 gridC(32, NBATCH);
  normalize_kernel<<<gridC, 256, 0, stream>>>(x, inv_scale, out);
}

// Round 2
// 106.886 us; speedup vs baseline: 1.4164x; 1.4164x over previous
//
#include <hip/hip_runtime.h>

#define NBATCH 64
#define NV 50000
#define NT 100000
#define FPB (NV * 3)          /* floats per batch = 150000 */

#define XCDS 8
#define SLOTS 256             /* blocks per XCD (32 CUs x 8 blocks) */
#define GRID_VOL (XCDS * SLOTS)   /* 2048 blocks, all co-resident at 12 VGPR */
#define BATCH_PER_XCD (NBATCH / XCDS)   /* 8 */

// XCD-locality gather: linear block -> xcd = L&7 (round-robin dispatch).
// XCD x owns batches [8x, 8x+8); every block on that XCD sweeps them in the
// same order, so the 600 KB batch slice stays resident in that XCD's 4 MB L2.
__global__ __launch_bounds__(256) void vol_partial_kernel(
    const float* __restrict__ x, const int* __restrict__ M,
    double* __restrict__ partials) {
  const int L = blockIdx.x;
  const int xcd = L & (XCDS - 1);
  const int slot = L >> 3;  // 0..255
  __shared__ double lds[4];
  const int lane = threadIdx.x & 63;
  const int wave = threadIdx.x >> 6;

  for (int bi = 0; bi < BATCH_PER_XCD; ++bi) {
    const int b = xcd * BATCH_PER_XCD + bi;
    const float* __restrict__ xv = x + (size_t)b * FPB;
    double acc = 0.0;
    for (int t = slot * 256 + threadIdx.x; t < NT; t += SLOTS * 256) {
      const int i0 = M[3 * t + 0];
      const int i1 = M[3 * t + 1];
      const int i2 = M[3 * t + 2];
      const float a0 = xv[3 * i0 + 0], a1 = xv[3 * i0 + 1], a2 = xv[3 * i0 + 2];
      const float b0 = xv[3 * i1 + 0], b1 = xv[3 * i1 + 1], b2 = xv[3 * i1 + 2];
      const float c0 = xv[3 * i2 + 0], c1 = xv[3 * i2 + 1], c2 = xv[3 * i2 + 2];
      const float cx = b1 * c2 - b2 * c1;
      const float cy = b2 * c0 - b0 * c2;
      const float cz = b0 * c1 - b1 * c0;
      const float det = a0 * cx + a1 * cy + a2 * cz;
      acc += (double)fabsf(det);
    }
    // wave (64-lane) reduce, then 4-wave LDS reduce — fixed order, deterministic
    #pragma unroll
    for (int off = 32; off > 0; off >>= 1) acc += __shfl_down(acc, off, 64);
    if (lane == 0) lds[wave] = acc;
    __syncthreads();
    if (threadIdx.x == 0) {
      partials[(size_t)b * SLOTS + slot] = (lds[0] + lds[1]) + (lds[2] + lds[3]);
    }
    __syncthreads();  // lds reused next batch iteration
  }
}

__global__ __launch_bounds__(256) void finalize_kernel(
    const double* __restrict__ partials, float* __restrict__ inv_scale) {
  const int b = blockIdx.x;
  double v = partials[(size_t)b * SLOTS + threadIdx.x];
  #pragma unroll
  for (int off = 32; off > 0; off >>= 1) v += __shfl_down(v, off, 64);
  __shared__ double lds[4];
  const int lane = threadIdx.x & 63;
  const int wave = threadIdx.x >> 6;
  if (lane == 0) lds[wave] = v;
  __syncthreads();
  if (threadIdx.x == 0) {
    const double vol = ((lds[0] + lds[1]) + (lds[2] + lds[3])) / 6.0;
    inv_scale[b] = (float)(1.0 / cbrt(vol));
  }
}

__global__ __launch_bounds__(256) void normalize_kernel(
    const float* __restrict__ x, const float* __restrict__ inv_scale,
    float* __restrict__ out) {
  const int b = blockIdx.y;
  const float s = inv_scale[b];
  const float4* __restrict__ xin =
      reinterpret_cast<const float4*>(x + (size_t)b * FPB);
  float4* __restrict__ o = reinterpret_cast<float4*>(out + (size_t)b * FPB);
  const int n4 = FPB / 4;  // 37500
  const int stride = blockDim.x * gridDim.x;
  for (int i = blockIdx.x * blockDim.x + threadIdx.x; i < n4; i += stride) {
    float4 v = xin[i];
    v.x *= s; v.y *= s; v.z *= s; v.w *= s;
    o[i] = v;
  }
}

extern "C" void kernel_launch(void* const* d_in, const int* in_sizes, int n_in,
                              void* d_out, int out_size, void* d_ws, size_t ws_size,
                              hipStream_t stream) {
  const float* x = (const float*)d_in[0];
  const int* M = (const int*)d_in[1];
  float* out = (float*)d_out;

  double* partials = (double*)d_ws;                        // 64*256 doubles = 128 KiB
  float* inv_scale = (float*)(partials + NBATCH * SLOTS);  // 64 floats

  vol_partial_kernel<<<GRID_VOL, 256, 0, stream>>>(x, M, partials);
  finalize_kernel<<<NBATCH, SLOTS, 0, stream>>>(partials, inv_scale);

  dim3 gridC(32, NBATCH);
  normalize_kernel<<<gridC, 256, 0, stream>>>(x, inv_scale, out);
}

// Round 3
// 81.780 us; speedup vs baseline: 1.8512x; 1.3070x over previous
//
#include <hip/hip_runtime.h>

#define NBATCH 64
#define NV 50000
#define NT 100000
#define FPB (NV * 3)          /* floats per batch = 150000 */

/* ---------------- transposed-gather path ---------------- */

#define GBLOCKS 2048
#define NWAVES (GBLOCKS * 4)            /* 8192 waves, ~13 triangles each */
#define XT_FLOATS ((size_t)FPB * NBATCH)            /* 9.6e6 floats */
#define WS_NEED (XT_FLOATS * 4 + (size_t)NWAVES * NBATCH * 8 + 256)

// x[b][f] -> xT[f][b], 64x64 LDS tiles, conflict-free (stride 65)
__global__ __launch_bounds__(256) void transpose_kernel(
    const float* __restrict__ x, float* __restrict__ xT) {
  __shared__ float tile[64][65];
  const int tx = threadIdx.x & 63;
  const int ty = threadIdx.x >> 6;  // 0..3
  const int f0 = blockIdx.x * 64;
  const int fl = f0 + tx;
  #pragma unroll
  for (int i = ty; i < 64; i += 4) {
    if (fl < FPB) tile[i][tx] = x[(size_t)i * FPB + fl];
  }
  __syncthreads();
  #pragma unroll
  for (int i = ty; i < 64; i += 4) {
    const int f = f0 + i;
    if (f < FPB) xT[(size_t)f * 64 + tx] = tile[tx][i];
  }
}

// one wave = one triangle range, lane = batch; 9 coalesced 256B loads/triangle
__global__ __launch_bounds__(256) void gather_det_kernel(
    const float* __restrict__ xT, const int* __restrict__ M,
    double* __restrict__ partials) {
  const int w = blockIdx.x * 4 + (threadIdx.x >> 6);
  const int lane = threadIdx.x & 63;
  const int per = (NT + NWAVES - 1) / NWAVES;  // 13
  const int t0 = w * per;
  const int t1 = min(t0 + per, NT);
  double acc = 0.0;
  #pragma unroll 2
  for (int t = t0; t < t1; ++t) {
    const int i0 = M[3 * t + 0];
    const int i1 = M[3 * t + 1];
    const int i2 = M[3 * t + 2];
    const float* p0 = xT + (size_t)(3 * i0) * 64 + lane;
    const float* p1 = xT + (size_t)(3 * i1) * 64 + lane;
    const float* p2 = xT + (size_t)(3 * i2) * 64 + lane;
    const float a0 = p0[0], a1 = p0[64], a2 = p0[128];
    const float b0 = p1[0], b1 = p1[64], b2 = p1[128];
    const float c0 = p2[0], c1 = p2[64], c2 = p2[128];
    const float cx = b1 * c2 - b2 * c1;
    const float cy = b2 * c0 - b0 * c2;
    const float cz = b0 * c1 - b1 * c0;
    const float det = a0 * cx + a1 * cy + a2 * cz;
    acc += (double)fabsf(det);
  }
  partials[(size_t)w * NBATCH + lane] = acc;  // coalesced, fixed order
}

__global__ __launch_bounds__(256) void finalize_t_kernel(
    const double* __restrict__ partials, float* __restrict__ inv_scale) {
  const int b = blockIdx.x;
  double acc = 0.0;
  for (int w = threadIdx.x; w < NWAVES; w += 256)
    acc += partials[(size_t)w * NBATCH + b];
  #pragma unroll
  for (int off = 32; off > 0; off >>= 1) acc += __shfl_down(acc, off, 64);
  __shared__ double lds[4];
  const int lane = threadIdx.x & 63;
  const int wave = threadIdx.x >> 6;
  if (lane == 0) lds[wave] = acc;
  __syncthreads();
  if (threadIdx.x == 0) {
    const double vol = ((lds[0] + lds[1]) + (lds[2] + lds[3])) / 6.0;
    inv_scale[b] = (float)(1.0 / cbrt(vol));
  }
}

/* ---------------- fallback path (round-2, XCD-local) ---------------- */

#define XCDS 8
#define SLOTS 256
#define GRID_VOL (XCDS * SLOTS)
#define BATCH_PER_XCD (NBATCH / XCDS)

__global__ __launch_bounds__(256) void vol_partial_kernel(
    const float* __restrict__ x, const int* __restrict__ M,
    double* __restrict__ partials) {
  const int L = blockIdx.x;
  const int xcd = L & (XCDS - 1);
  const int slot = L >> 3;
  __shared__ double lds[4];
  const int lane = threadIdx.x & 63;
  const int wave = threadIdx.x >> 6;
  for (int bi = 0; bi < BATCH_PER_XCD; ++bi) {
    const int b = xcd * BATCH_PER_XCD + bi;
    const float* __restrict__ xv = x + (size_t)b * FPB;
    double acc = 0.0;
    for (int t = slot * 256 + threadIdx.x; t < NT; t += SLOTS * 256) {
      const int i0 = M[3 * t + 0], i1 = M[3 * t + 1], i2 = M[3 * t + 2];
      const float a0 = xv[3 * i0], a1 = xv[3 * i0 + 1], a2 = xv[3 * i0 + 2];
      const float b0 = xv[3 * i1], b1 = xv[3 * i1 + 1], b2 = xv[3 * i1 + 2];
      const float c0 = xv[3 * i2], c1 = xv[3 * i2 + 1], c2 = xv[3 * i2 + 2];
      const float det = a0 * (b1 * c2 - b2 * c1) + a1 * (b2 * c0 - b0 * c2) +
                        a2 * (b0 * c1 - b1 * c0);
      acc += (double)fabsf(det);
    }
    #pragma unroll
    for (int off = 32; off > 0; off >>= 1) acc += __shfl_down(acc, off, 64);
    if (lane == 0) lds[wave] = acc;
    __syncthreads();
    if (threadIdx.x == 0)
      partials[(size_t)b * SLOTS + slot] = (lds[0] + lds[1]) + (lds[2] + lds[3]);
    __syncthreads();
  }
}

__global__ __launch_bounds__(256) void finalize_kernel(
    const double* __restrict__ partials, float* __restrict__ inv_scale) {
  const int b = blockIdx.x;
  double v = partials[(size_t)b * SLOTS + threadIdx.x];
  #pragma unroll
  for (int off = 32; off > 0; off >>= 1) v += __shfl_down(v, off, 64);
  __shared__ double lds[4];
  const int lane = threadIdx.x & 63;
  const int wave = threadIdx.x >> 6;
  if (lane == 0) lds[wave] = v;
  __syncthreads();
  if (threadIdx.x == 0) {
    const double vol = ((lds[0] + lds[1]) + (lds[2] + lds[3])) / 6.0;
    inv_scale[b] = (float)(1.0 / cbrt(vol));
  }
}

/* ---------------- shared normalize ---------------- */

__global__ __launch_bounds__(256) void normalize_kernel(
    const float* __restrict__ x, const float* __restrict__ inv_scale,
    float* __restrict__ out) {
  const int b = blockIdx.y;
  const float s = inv_scale[b];
  const float4* __restrict__ xin =
      reinterpret_cast<const float4*>(x + (size_t)b * FPB);
  float4* __restrict__ o = reinterpret_cast<float4*>(out + (size_t)b * FPB);
  const int n4 = FPB / 4;  // 37500
  const int stride = blockDim.x * gridDim.x;
  for (int i = blockIdx.x * blockDim.x + threadIdx.x; i < n4; i += stride) {
    float4 v = xin[i];
    v.x *= s; v.y *= s; v.z *= s; v.w *= s;
    o[i] = v;
  }
}

extern "C" void kernel_launch(void* const* d_in, const int* in_sizes, int n_in,
                              void* d_out, int out_size, void* d_ws, size_t ws_size,
                              hipStream_t stream) {
  const float* x = (const float*)d_in[0];
  const int* M = (const int*)d_in[1];
  float* out = (float*)d_out;

  float* inv_scale;
  if (ws_size >= WS_NEED) {
    float* xT = (float*)d_ws;
    double* partials = (double*)((char*)d_ws + XT_FLOATS * 4);
    inv_scale = (float*)(partials + (size_t)NWAVES * NBATCH);

    const int ntiles = (FPB + 63) / 64;  // 2344
    transpose_kernel<<<ntiles, 256, 0, stream>>>(x, xT);
    gather_det_kernel<<<GBLOCKS, 256, 0, stream>>>(xT, M, partials);
    finalize_t_kernel<<<NBATCH, 256, 0, stream>>>(partials, inv_scale);
  } else {
    double* partials = (double*)d_ws;
    inv_scale = (float*)(partials + NBATCH * SLOTS);
    vol_partial_kernel<<<GRID_VOL, 256, 0, stream>>>(x, M, partials);
    finalize_kernel<<<NBATCH, SLOTS, 0, stream>>>(partials, inv_scale);
  }

  dim3 gridC(32, NBATCH);
  normalize_kernel<<<gridC, 256, 0, stream>>>(x, inv_scale, out);
}

// Round 5
// 65.965 us; speedup vs baseline: 2.2950x; 1.2397x over previous
//
#include <hip/hip_runtime.h>
#include <hip/hip_fp16.h>

#define NBATCH 64
#define NV 50000
#define NT 100000
#define FPB (NV * 3)          /* floats per batch = 150000 */

typedef float f32x4 __attribute__((ext_vector_type(4)));

/* ---------------- transposed fp16-gather path ---------------- */

#define GBLOCKS 2048
#define NWAVES (GBLOCKS * 4)                 /* 8192 waves, 13 triangles each */
#define XH_HALVES ((size_t)FPB * NBATCH)     /* 9.6e6 halves = 19.2 MB */
#define WS_NEED (XH_HALVES * 2 + (size_t)NWAVES * NBATCH * 8 + 256)

// x[b][f] -> three fp16 planes xH[c][v][b], 64x64 LDS tiles (stride 65).
// Plane layout: each (c,v) row is 64 halves = one 128B cache line.
__global__ __launch_bounds__(256) void transpose_kernel(
    const float* __restrict__ x, __half* __restrict__ xH) {
  __shared__ float tile[64][65];
  const int tx = threadIdx.x & 63;   // f-offset on read, batch on write
  const int ty = threadIdx.x >> 6;   // 0..3
  const int f0 = blockIdx.x * 64;
  const int fl = f0 + tx;
  #pragma unroll
  for (int i = ty; i < 64; i += 4) {
    if (fl < FPB) tile[i][tx] = x[(size_t)i * FPB + fl];
  }
  __syncthreads();
  #pragma unroll
  for (int i = ty; i < 64; i += 4) {
    const int f = f0 + i;
    if (f < FPB) {
      const int v = f / 3, c = f - 3 * v;
      xH[((size_t)c * NV + v) * 64 + tx] = __float2half(tile[tx][i]);
    }
  }
}

// one wave = 13 triangles, lane = batch; per (c,vertex) load = one 128B line
__global__ __launch_bounds__(256) void gather_det_kernel(
    const __half* __restrict__ xH, const int* __restrict__ M,
    double* __restrict__ partials) {
  const int w = blockIdx.x * 4 + (threadIdx.x >> 6);
  const int lane = threadIdx.x & 63;
  const int per = (NT + NWAVES - 1) / NWAVES;  // 13
  const int t0 = w * per;
  const int t1 = min(t0 + per, NT);
  const __half* __restrict__ pX = xH;                       // plane c=0
  const __half* __restrict__ pY = xH + (size_t)NV * 64;     // plane c=1
  const __half* __restrict__ pZ = xH + (size_t)2 * NV * 64; // plane c=2
  double acc = 0.0;
  #pragma unroll 4
  for (int t = t0; t < t1; ++t) {
    const int i0 = M[3 * t + 0];
    const int i1 = M[3 * t + 1];
    const int i2 = M[3 * t + 2];
    const float a0 = __half2float(pX[(size_t)i0 * 64 + lane]);
    const float a1 = __half2float(pY[(size_t)i0 * 64 + lane]);
    const float a2 = __half2float(pZ[(size_t)i0 * 64 + lane]);
    const float b0 = __half2float(pX[(size_t)i1 * 64 + lane]);
    const float b1 = __half2float(pY[(size_t)i1 * 64 + lane]);
    const float b2 = __half2float(pZ[(size_t)i1 * 64 + lane]);
    const float c0 = __half2float(pX[(size_t)i2 * 64 + lane]);
    const float c1 = __half2float(pY[(size_t)i2 * 64 + lane]);
    const float c2 = __half2float(pZ[(size_t)i2 * 64 + lane]);
    const float cx = b1 * c2 - b2 * c1;
    const float cy = b2 * c0 - b0 * c2;
    const float cz = b0 * c1 - b1 * c0;
    const float det = a0 * cx + a1 * cy + a2 * cz;
    acc += (double)fabsf(det);
  }
  partials[(size_t)w * NBATCH + lane] = acc;  // coalesced, fixed order
}

__global__ __launch_bounds__(256) void finalize_t_kernel(
    const double* __restrict__ partials, float* __restrict__ inv_scale) {
  const int b = blockIdx.x;
  double acc = 0.0;
  for (int w = threadIdx.x; w < NWAVES; w += 256)
    acc += partials[(size_t)w * NBATCH + b];
  #pragma unroll
  for (int off = 32; off > 0; off >>= 1) acc += __shfl_down(acc, off, 64);
  __shared__ double lds[4];
  const int lane = threadIdx.x & 63;
  const int wave = threadIdx.x >> 6;
  if (lane == 0) lds[wave] = acc;
  __syncthreads();
  if (threadIdx.x == 0) {
    const double vol = ((lds[0] + lds[1]) + (lds[2] + lds[3])) / 6.0;
    inv_scale[b] = (float)(1.0 / cbrt(vol));
  }
}

/* ---------------- fallback path (round-2, XCD-local) ---------------- */

#define XCDS 8
#define SLOTS 256
#define GRID_VOL (XCDS * SLOTS)
#define BATCH_PER_XCD (NBATCH / XCDS)

__global__ __launch_bounds__(256) void vol_partial_kernel(
    const float* __restrict__ x, const int* __restrict__ M,
    double* __restrict__ partials) {
  const int L = blockIdx.x;
  const int xcd = L & (XCDS - 1);
  const int slot = L >> 3;
  __shared__ double lds[4];
  const int lane = threadIdx.x & 63;
  const int wave = threadIdx.x >> 6;
  for (int bi = 0; bi < BATCH_PER_XCD; ++bi) {
    const int b = xcd * BATCH_PER_XCD + bi;
    const float* __restrict__ xv = x + (size_t)b * FPB;
    double acc = 0.0;
    for (int t = slot * 256 + threadIdx.x; t < NT; t += SLOTS * 256) {
      const int i0 = M[3 * t + 0], i1 = M[3 * t + 1], i2 = M[3 * t + 2];
      const float a0 = xv[3 * i0], a1 = xv[3 * i0 + 1], a2 = xv[3 * i0 + 2];
      const float b0 = xv[3 * i1], b1 = xv[3 * i1 + 1], b2 = xv[3 * i1 + 2];
      const float c0 = xv[3 * i2], c1 = xv[3 * i2 + 1], c2 = xv[3 * i2 + 2];
      const float det = a0 * (b1 * c2 - b2 * c1) + a1 * (b2 * c0 - b0 * c2) +
                        a2 * (b0 * c1 - b1 * c0);
      acc += (double)fabsf(det);
    }
    #pragma unroll
    for (int off = 32; off > 0; off >>= 1) acc += __shfl_down(acc, off, 64);
    if (lane == 0) lds[wave] = acc;
    __syncthreads();
    if (threadIdx.x == 0)
      partials[(size_t)b * SLOTS + slot] = (lds[0] + lds[1]) + (lds[2] + lds[3]);
    __syncthreads();
  }
}

__global__ __launch_bounds__(256) void finalize_kernel(
    const double* __restrict__ partials, float* __restrict__ inv_scale) {
  const int b = blockIdx.x;
  double v = partials[(size_t)b * SLOTS + threadIdx.x];
  #pragma unroll
  for (int off = 32; off > 0; off >>= 1) v += __shfl_down(v, off, 64);
  __shared__ double lds[4];
  const int lane = threadIdx.x & 63;
  const int wave = threadIdx.x >> 6;
  if (lane == 0) lds[wave] = v;
  __syncthreads();
  if (threadIdx.x == 0) {
    const double vol = ((lds[0] + lds[1]) + (lds[2] + lds[3])) / 6.0;
    inv_scale[b] = (float)(1.0 / cbrt(vol));
  }
}

/* ---------------- shared normalize ---------------- */

__global__ __launch_bounds__(256) void normalize_kernel(
    const float* __restrict__ x, const float* __restrict__ inv_scale,
    float* __restrict__ out) {
  const int b = blockIdx.y;
  const float s = inv_scale[b];
  const f32x4* __restrict__ xin =
      reinterpret_cast<const f32x4*>(x + (size_t)b * FPB);
  f32x4* __restrict__ o = reinterpret_cast<f32x4*>(out + (size_t)b * FPB);
  const int n4 = FPB / 4;  // 37500
  const int stride = blockDim.x * gridDim.x;
  for (int i = blockIdx.x * blockDim.x + threadIdx.x; i < n4; i += stride) {
    f32x4 v = xin[i];
    v *= s;
    __builtin_nontemporal_store(v, &o[i]);  // out never re-read: keep L3 for xH/x
  }
}

extern "C" void kernel_launch(void* const* d_in, const int* in_sizes, int n_in,
                              void* d_out, int out_size, void* d_ws, size_t ws_size,
                              hipStream_t stream) {
  const float* x = (const float*)d_in[0];
  const int* M = (const int*)d_in[1];
  float* out = (float*)d_out;

  float* inv_scale;
  if (ws_size >= WS_NEED) {
    __half* xH = (__half*)d_ws;
    double* partials = (double*)((char*)d_ws + XH_HALVES * 2);
    inv_scale = (float*)(partials + (size_t)NWAVES * NBATCH);

    const int ntiles = (FPB + 63) / 64;  // 2344
    transpose_kernel<<<ntiles, 256, 0, stream>>>(x, xH);
    gather_det_kernel<<<GBLOCKS, 256, 0, stream>>>(xH, M, partials);
    finalize_t_kernel<<<NBATCH, 256, 0, stream>>>(partials, inv_scale);
  } else {
    double* partials = (double*)d_ws;
    inv_scale = (float*)(partials + NBATCH * SLOTS);
    vol_partial_kernel<<<GRID_VOL, 256, 0, stream>>>(x, M, partials);
    finalize_kernel<<<NBATCH, SLOTS, 0, stream>>>(partials, inv_scale);
  }

  dim3 gridC(32, NBATCH);
  normalize_kernel<<<gridC, 256, 0, stream>>>(x, inv_scale, out);
}

// Round 6
// 60.071 us; speedup vs baseline: 2.5202x; 1.0981x over previous
//
#include <hip/hip_runtime.h>
#include <hip/hip_fp16.h>

#define NBATCH 64
#define NV 50000
#define NT 100000
#define FPB (NV * 3)          /* floats per batch = 150000 */

typedef float f32x4 __attribute__((ext_vector_type(4)));
typedef int i32x4 __attribute__((ext_vector_type(4)));

/* ---------------- transposed fp16-gather path ---------------- */

#define GWAVES 4096                          /* gather waves (1024 blocks) */
#define NGROUP (NT / 8)                      /* 12500 groups of 8 triangles */
#define XH_HALVES ((size_t)FPB * NBATCH)     /* 9.6e6 halves = 19.2 MB */
#define WS_NEED (XH_HALVES * 2 + (size_t)GWAVES * NBATCH * 8 + 256)

// x[b][f] -> three fp16 planes xH[c][v][b]; each (c,v) row = 64 halves = one
// aligned 128B cache line.
__global__ __launch_bounds__(256) void transpose_kernel(
    const float* __restrict__ x, __half* __restrict__ xH) {
  __shared__ float tile[64][65];
  const int tx = threadIdx.x & 63;   // f-offset on read, batch on write
  const int ty = threadIdx.x >> 6;   // 0..3
  const int f0 = blockIdx.x * 64;
  const int fl = f0 + tx;
  #pragma unroll
  for (int i = ty; i < 64; i += 4) {
    if (fl < FPB) tile[i][tx] = x[(size_t)i * FPB + fl];
  }
  __syncthreads();
  #pragma unroll
  for (int i = ty; i < 64; i += 4) {
    const int f = f0 + i;
    if (f < FPB) {
      const int v = f / 3, c = f - 3 * v;
      xH[((size_t)c * NV + v) * 64 + tx] = __float2half(tile[tx][i]);
    }
  }
}

__device__ __forceinline__ float hext(const i32x4& v, int j) {
  const int word = v[j >> 1];
  const __half2 h = __builtin_bit_cast(__half2, word);
  return (j & 1) ? __high2float(h) : __low2float(h);
}

// 8-triangle packed gather: one dwordx4 wave-load = 8 full 128B rows (8 tris'
// same coord/vertex slot). lane = (tri_sub = lane>>3, batch_octet = lane&7).
// 9 loads per 8 triangles (vs 72 unpacked) -> L3-byte-bound.
__global__ __launch_bounds__(256) void gather_det8_kernel(
    const __half* __restrict__ xH, const int* __restrict__ M,
    double* __restrict__ partials) {
  const int w = blockIdx.x * 4 + (threadIdx.x >> 6);
  const int lane = threadIdx.x & 63;
  const int sub = lane >> 3;       // which triangle of the group (0..7)
  const int boct = lane & 7;       // batch octet: batches boct*8 .. boct*8+7
  const __half* __restrict__ pX = xH;
  const __half* __restrict__ pY = xH + (size_t)NV * 64;
  const __half* __restrict__ pZ = xH + (size_t)2 * NV * 64;
  const size_t o = 8 * boct;       // halve offset within a row (16B aligned)

  double acc[8];
  #pragma unroll
  for (int j = 0; j < 8; ++j) acc[j] = 0.0;

  for (int g = w; g < NGROUP; g += GWAVES) {
    const int t = g * 8 + sub;
    const int i0 = M[3 * t + 0];
    const int i1 = M[3 * t + 1];
    const int i2 = M[3 * t + 2];
    const i32x4 A0 = *(const i32x4*)(pX + (size_t)i0 * 64 + o);
    const i32x4 A1 = *(const i32x4*)(pY + (size_t)i0 * 64 + o);
    const i32x4 A2 = *(const i32x4*)(pZ + (size_t)i0 * 64 + o);
    const i32x4 B0 = *(const i32x4*)(pX + (size_t)i1 * 64 + o);
    const i32x4 B1 = *(const i32x4*)(pY + (size_t)i1 * 64 + o);
    const i32x4 B2 = *(const i32x4*)(pZ + (size_t)i1 * 64 + o);
    const i32x4 C0 = *(const i32x4*)(pX + (size_t)i2 * 64 + o);
    const i32x4 C1 = *(const i32x4*)(pY + (size_t)i2 * 64 + o);
    const i32x4 C2 = *(const i32x4*)(pZ + (size_t)i2 * 64 + o);
    #pragma unroll
    for (int j = 0; j < 8; ++j) {
      const float a0 = hext(A0, j), a1 = hext(A1, j), a2 = hext(A2, j);
      const float b0 = hext(B0, j), b1 = hext(B1, j), b2 = hext(B2, j);
      const float c0 = hext(C0, j), c1 = hext(C1, j), c2 = hext(C2, j);
      const float det = a0 * (b1 * c2 - b2 * c1) +
                        a1 * (b2 * c0 - b0 * c2) +
                        a2 * (b0 * c1 - b1 * c0);
      acc[j] += (double)fabsf(det);
    }
  }
  // reduce over tri-subset lanes (bits 3..5) — fixed order, deterministic
  #pragma unroll
  for (int j = 0; j < 8; ++j) {
    acc[j] += __shfl_xor(acc[j], 8, 64);
    acc[j] += __shfl_xor(acc[j], 16, 64);
    acc[j] += __shfl_xor(acc[j], 32, 64);
  }
  if (sub == 0) {
    #pragma unroll
    for (int j = 0; j < 8; ++j)
      partials[(size_t)w * NBATCH + boct * 8 + j] = acc[j];
  }
}

__global__ __launch_bounds__(256) void finalize_t_kernel(
    const double* __restrict__ partials, float* __restrict__ inv_scale) {
  const int b = blockIdx.x;
  double acc = 0.0;
  for (int w = threadIdx.x; w < GWAVES; w += 256)
    acc += partials[(size_t)w * NBATCH + b];
  #pragma unroll
  for (int off = 32; off > 0; off >>= 1) acc += __shfl_down(acc, off, 64);
  __shared__ double lds[4];
  const int lane = threadIdx.x & 63;
  const int wave = threadIdx.x >> 6;
  if (lane == 0) lds[wave] = acc;
  __syncthreads();
  if (threadIdx.x == 0) {
    const double vol = ((lds[0] + lds[1]) + (lds[2] + lds[3])) / 6.0;
    inv_scale[b] = (float)(1.0 / cbrt(vol));
  }
}

/* ---------------- fallback path (round-2, XCD-local) ---------------- */

#define XCDS 8
#define SLOTS 256
#define GRID_VOL (XCDS * SLOTS)
#define BATCH_PER_XCD (NBATCH / XCDS)

__global__ __launch_bounds__(256) void vol_partial_kernel(
    const float* __restrict__ x, const int* __restrict__ M,
    double* __restrict__ partials) {
  const int L = blockIdx.x;
  const int xcd = L & (XCDS - 1);
  const int slot = L >> 3;
  __shared__ double lds[4];
  const int lane = threadIdx.x & 63;
  const int wave = threadIdx.x >> 6;
  for (int bi = 0; bi < BATCH_PER_XCD; ++bi) {
    const int b = xcd * BATCH_PER_XCD + bi;
    const float* __restrict__ xv = x + (size_t)b * FPB;
    double acc = 0.0;
    for (int t = slot * 256 + threadIdx.x; t < NT; t += SLOTS * 256) {
      const int i0 = M[3 * t + 0], i1 = M[3 * t + 1], i2 = M[3 * t + 2];
      const float a0 = xv[3 * i0], a1 = xv[3 * i0 + 1], a2 = xv[3 * i0 + 2];
      const float b0 = xv[3 * i1], b1 = xv[3 * i1 + 1], b2 = xv[3 * i1 + 2];
      const float c0 = xv[3 * i2], c1 = xv[3 * i2 + 1], c2 = xv[3 * i2 + 2];
      const float det = a0 * (b1 * c2 - b2 * c1) + a1 * (b2 * c0 - b0 * c2) +
                        a2 * (b0 * c1 - b1 * c0);
      acc += (double)fabsf(det);
    }
    #pragma unroll
    for (int off = 32; off > 0; off >>= 1) acc += __shfl_down(acc, off, 64);
    if (lane == 0) lds[wave] = acc;
    __syncthreads();
    if (threadIdx.x == 0)
      partials[(size_t)b * SLOTS + slot] = (lds[0] + lds[1]) + (lds[2] + lds[3]);
    __syncthreads();
  }
}

__global__ __launch_bounds__(256) void finalize_kernel(
    const double* __restrict__ partials, float* __restrict__ inv_scale) {
  const int b = blockIdx.x;
  double v = partials[(size_t)b * SLOTS + threadIdx.x];
  #pragma unroll
  for (int off = 32; off > 0; off >>= 1) v += __shfl_down(v, off, 64);
  __shared__ double lds[4];
  const int lane = threadIdx.x & 63;
  const int wave = threadIdx.x >> 6;
  if (lane == 0) lds[wave] = v;
  __syncthreads();
  if (threadIdx.x == 0) {
    const double vol = ((lds[0] + lds[1]) + (lds[2] + lds[3])) / 6.0;
    inv_scale[b] = (float)(1.0 / cbrt(vol));
  }
}

/* ---------------- shared normalize ---------------- */

__global__ __launch_bounds__(256) void normalize_kernel(
    const float* __restrict__ x, const float* __restrict__ inv_scale,
    float* __restrict__ out) {
  const int b = blockIdx.y;
  const float s = inv_scale[b];
  const f32x4* __restrict__ xin =
      reinterpret_cast<const f32x4*>(x + (size_t)b * FPB);
  f32x4* __restrict__ o = reinterpret_cast<f32x4*>(out + (size_t)b * FPB);
  const int n4 = FPB / 4;  // 37500
  const int stride = blockDim.x * gridDim.x;
  for (int i = blockIdx.x * blockDim.x + threadIdx.x; i < n4; i += stride) {
    f32x4 v = xin[i];
    v *= s;
    __builtin_nontemporal_store(v, &o[i]);  // out never re-read: keep L3 warm
  }
}

extern "C" void kernel_launch(void* const* d_in, const int* in_sizes, int n_in,
                              void* d_out, int out_size, void* d_ws, size_t ws_size,
                              hipStream_t stream) {
  const float* x = (const float*)d_in[0];
  const int* M = (const int*)d_in[1];
  float* out = (float*)d_out;

  float* inv_scale;
  if (ws_size >= WS_NEED) {
    __half* xH = (__half*)d_ws;
    double* partials = (double*)((char*)d_ws + XH_HALVES * 2);
    inv_scale = (float*)(partials + (size_t)GWAVES * NBATCH);

    const int ntiles = (FPB + 63) / 64;  // 2344
    transpose_kernel<<<ntiles, 256, 0, stream>>>(x, xH);
    gather_det8_kernel<<<GWAVES / 4, 256, 0, stream>>>(xH, M, partials);
    finalize_t_kernel<<<NBATCH, 256, 0, stream>>>(partials, inv_scale);
  } else {
    double* partials = (double*)d_ws;
    inv_scale = (float*)(partials + NBATCH * SLOTS);
    vol_partial_kernel<<<GRID_VOL, 256, 0, stream>>>(x, M, partials);
    finalize_kernel<<<NBATCH, SLOTS, 0, stream>>>(partials, inv_scale);
  }

  dim3 gridC(32, NBATCH);
  normalize_kernel<<<gridC, 256, 0, stream>>>(x, inv_scale, out);
}